// Round 1
// 2123.829 us; speedup vs baseline: 1.1802x; 1.1802x over previous
//
#include <hip/hip_runtime.h>
#include <stdint.h>

// B=2, T=32, N=256, E=1024, H=16, D=64, L=2, K=256, MAXLEN=512
// tokens = 16384, GEMMs/attention chunked in 2 x 8192 rows.
//
// Round N: main GEMM core rebuilt as 256x128-tile, BK=32, 512-thread,
// triple-buffered (144 KB LDS) pipeline with ONE s_barrier per K-step and
// counted s_waitcnt vmcnt(6) (prefetch depth 2), XOR LDS swizzle
// (slot ^= (row>>1)&3, inverse-swizzled global source so global_load_lds
// stays linear-dest), setprio around MFMA cluster, bijective XCD block
// swizzle. Replaces the 128x128 2-barrier core for qkvsplit + out-proj.

using f16x8 = __attribute__((ext_vector_type(8))) _Float16;
using f16x4 = __attribute__((ext_vector_type(4))) _Float16;
using f32x4 = __attribute__((ext_vector_type(4))) float;

__device__ __forceinline__ int tmap_dev(int m) {
    // temporal token m = (b*N+n)*T + t  ->  flat row (b*T+t)*N + n
    int bx = m >> 5;
    int s  = m & 31;
    int b  = bx >> 8;
    int n  = bx & 255;
    return (((b << 5) + s) << 8) + n;
}

__device__ __forceinline__ void load16(const _Float16* g, _Float16* l)
{
    __builtin_amdgcn_global_load_lds(
        (const __attribute__((address_space(1))) unsigned int*)g,
        (__attribute__((address_space(3))) unsigned int*)l,
        16, 0, 0);
}

__device__ __forceinline__ void split_f16(float v, _Float16& h, _Float16& l)
{
    h = (_Float16)v;
    l = (_Float16)(v - (float)h);
}

// ---------------------------------------------------------------------------
// x fp32 -> split f16 hi/lo (a=0 only, identity map). chunk-local dst.
// ---------------------------------------------------------------------------
__global__ __launch_bounds__(256)
void conv_act(const float* __restrict__ src, _Float16* __restrict__ dh,
              _Float16* __restrict__ dl, int m_off)
{
    int idx = blockIdx.x * 256 + threadIdx.x;
    int e = idx << 3;
    int ml = e >> 10, col = e & 1023;
    const float* s = src + (size_t)(m_off + ml) * 1024 + col;
    float4 a = *(const float4*)s;
    float4 b = *(const float4*)(s + 4);
    float vv[8] = {a.x, a.y, a.z, a.w, b.x, b.y, b.z, b.w};
    f16x8 vh, vl;
    #pragma unroll
    for (int r = 0; r < 8; r++) {
        _Float16 h, l;
        split_f16(vv[r], h, l);
        vh[r] = h; vl[r] = l;
    }
    *(f16x8*)(dh + (size_t)ml * 1024 + col) = vh;
    *(f16x8*)(dl + (size_t)ml * 1024 + col) = vl;
}

// ---------------------------------------------------------------------------
// Weight fp32 [1024][ncols] -> transposed split f16 [ncols][1024].
// ---------------------------------------------------------------------------
__global__ __launch_bounds__(256)
void conv_wT(const float* __restrict__ W, _Float16* __restrict__ Th,
             _Float16* __restrict__ Tl, int ncols)
{
    __shared__ float Ls[64][65];
    const int n0 = blockIdx.x * 64, k0 = blockIdx.y * 64;
    const int t = threadIdx.x;
    const int kk = t >> 4, nn = (t & 15) << 2;
    #pragma unroll
    for (int i = 0; i < 4; i++) {
        float4 v = *(const float4*)(W + (size_t)(k0 + kk + 16 * i) * ncols + n0 + nn);
        Ls[kk + 16 * i][nn + 0] = v.x; Ls[kk + 16 * i][nn + 1] = v.y;
        Ls[kk + 16 * i][nn + 2] = v.z; Ls[kk + 16 * i][nn + 3] = v.w;
    }
    __syncthreads();
    const int nl = t >> 4, kc = (t & 15) << 2;
    #pragma unroll
    for (int i = 0; i < 4; i++) {
        int n = nl + 16 * i;
        f16x4 hh, ll;
        #pragma unroll
        for (int c = 0; c < 4; c++) {
            _Float16 h, l;
            split_f16(Ls[kc + c][n], h, l);
            hh[c] = h; ll[c] = l;
        }
        *(f16x4*)(Th + (size_t)(n0 + n) * 1024 + k0 + kc) = hh;
        *(f16x4*)(Tl + (size_t)(n0 + n) * 1024 + k0 + kc) = ll;
    }
}

// ---------------------------------------------------------------------------
// OLD split-f16 MFMA GEMM core, tile 128x128, BK=32 (kept only for the
// narrow selection GEMM, EPI 0: fp32 C with scatter map).
// ---------------------------------------------------------------------------
template<int EPI>
__device__ __forceinline__ void gemm_core(
    const _Float16* __restrict__ Ah, const _Float16* __restrict__ Al,
    const _Float16* __restrict__ Wh, const _Float16* __restrict__ Wl,
    const float* __restrict__ bias,
    float* __restrict__ C, _Float16* __restrict__ Ch, _Float16* __restrict__ Cl,
    int ldc, int map_in, int m_off_in, int map_out, int m_off_out,
    int n0, int m0)
{
    __shared__ uint32_t smem_u[8512];
    _Float16* smem = (_Float16*)smem_u;
    _Float16* sAh = smem;
    _Float16* sAl = smem + 4096;
    _Float16* sBh = smem + 8192;
    _Float16* sBl = smem + 12288;

    const int tid = threadIdx.x;
    const int lane = tid & 63;
    const int wv = tid >> 6;
    const int fm = (wv >> 1) << 6;
    const int fn = (wv & 1) << 6;
    const int lm = lane & 15, lq = lane >> 4;

    f32x4 acc[4][4] = {};

    const int srow = tid >> 2;
    const int skc  = (tid & 3) << 3;
    const int gm0 = m_off_in + m0 + srow;
    const int gm1 = gm0 + 64;
    const int r0 = map_in ? tmap_dev(gm0) : gm0;
    const int r1 = map_in ? tmap_dev(gm1) : gm1;
    const _Float16* gAh0 = Ah + (size_t)r0 * 1024 + skc;
    const _Float16* gAh1 = Ah + (size_t)r1 * 1024 + skc;
    const _Float16* gAl0 = Al + (size_t)r0 * 1024 + skc;
    const _Float16* gAl1 = Al + (size_t)r1 * 1024 + skc;
    const _Float16* gB0 = Wh + (size_t)(n0 + srow) * 1024 + skc;
    const _Float16* gB1 = Wl + (size_t)(n0 + srow) * 1024 + skc;
    const int lo = tid << 3;

    for (int k0 = 0; k0 < 1024; k0 += 32) {
        load16(gAh0 + k0, sAh + lo);
        load16(gAh1 + k0, sAh + lo + 2048);
        load16(gAl0 + k0, sAl + lo);
        load16(gAl1 + k0, sAl + lo + 2048);
        load16(gB0 + k0,         sBh + lo);
        load16(gB0 + k0 + 65536, sBh + lo + 2048);
        load16(gB1 + k0,         sBl + lo);
        load16(gB1 + k0 + 65536, sBl + lo + 2048);
        __syncthreads();

        f16x8 ah[4], al[4], bh[4], bl[4];
        #pragma unroll
        for (int i = 0; i < 4; i++) {
            int ra = (fm + i * 16 + lm) * 32 + lq * 8;
            ah[i] = *(const f16x8*)(sAh + ra);
            al[i] = *(const f16x8*)(sAl + ra);
            int rb_ = (fn + i * 16 + lm) * 32 + lq * 8;
            bh[i] = *(const f16x8*)(sBh + rb_);
            bl[i] = *(const f16x8*)(sBl + rb_);
        }
        #pragma unroll
        for (int i = 0; i < 4; i++)
            #pragma unroll
            for (int j = 0; j < 4; j++) {
                acc[i][j] = __builtin_amdgcn_mfma_f32_16x16x32_f16(ah[i], bh[j], acc[i][j], 0, 0, 0);
                acc[i][j] = __builtin_amdgcn_mfma_f32_16x16x32_f16(ah[i], bl[j], acc[i][j], 0, 0, 0);
                acc[i][j] = __builtin_amdgcn_mfma_f32_16x16x32_f16(al[i], bh[j], acc[i][j], 0, 0, 0);
            }
        __syncthreads();
    }

    if (EPI == 0 || EPI == 1) {
        #pragma unroll
        for (int j = 0; j < 4; j++) {
            int n = n0 + fn + j * 16 + lm;
            float bb = bias[n];
            #pragma unroll
            for (int i = 0; i < 4; i++) {
                #pragma unroll
                for (int r = 0; r < 4; r++) {
                    int gm = m_off_out + m0 + fm + i * 16 + lq * 4 + r;
                    int row = map_out ? tmap_dev(gm) : gm;
                    float v = acc[i][j][r] + bb;
                    if (EPI == 0) {
                        C[(size_t)row * ldc + n] = v;
                    } else {
                        _Float16 h, l;
                        split_f16(v, h, l);
                        Ch[(size_t)row * 1024 + n] = h;
                        Cl[(size_t)row * 1024 + n] = l;
                    }
                }
            }
        }
    } else {
        const int fmh = fm >> 6;
        #pragma unroll
        for (int mh = 0; mh < 2; mh++) {
            __syncthreads();
            if (fmh == mh) {
                #pragma unroll
                for (int j = 0; j < 4; j++) {
                    int n = fn + j * 16 + lm;
                    float bb = bias[n0 + n];
                    #pragma unroll
                    for (int i = 0; i < 4; i++) {
                        #pragma unroll
                        for (int r = 0; r < 4; r++) {
                            float v = acc[i][j][r] + bb;
                            _Float16 h, l;
                            split_f16(v, h, l);
                            uint32_t ph = (uint32_t)__builtin_bit_cast(unsigned short, h);
                            uint32_t pl = (uint32_t)__builtin_bit_cast(unsigned short, l);
                            smem_u[(i * 16 + lq * 4 + r) * 133 + n] = ph | (pl << 16);
                        }
                    }
                }
            }
            __syncthreads();
            #pragma unroll
            for (int g = 0; g < 8; g++) {
                int u = tid + g * 256;
                int nn = u >> 4;
                int mg = (u & 15) << 2;
                uint32_t p0 = smem_u[(mg + 0) * 133 + nn];
                uint32_t p1 = smem_u[(mg + 1) * 133 + nn];
                uint32_t p2 = smem_u[(mg + 2) * 133 + nn];
                uint32_t p3 = smem_u[(mg + 3) * 133 + nn];
                f16x4 hh, ll;
                hh[0] = __builtin_bit_cast(_Float16, (unsigned short)(p0 & 0xffff));
                hh[1] = __builtin_bit_cast(_Float16, (unsigned short)(p1 & 0xffff));
                hh[2] = __builtin_bit_cast(_Float16, (unsigned short)(p2 & 0xffff));
                hh[3] = __builtin_bit_cast(_Float16, (unsigned short)(p3 & 0xffff));
                ll[0] = __builtin_bit_cast(_Float16, (unsigned short)(p0 >> 16));
                ll[1] = __builtin_bit_cast(_Float16, (unsigned short)(p1 >> 16));
                ll[2] = __builtin_bit_cast(_Float16, (unsigned short)(p2 >> 16));
                ll[3] = __builtin_bit_cast(_Float16, (unsigned short)(p3 >> 16));
                size_t off = (size_t)(n0 + nn) * 8192 + (m0 + mh * 64 + mg);
                *(f16x4*)(Ch + off) = hh;
                *(f16x4*)(Cl + off) = ll;
            }
        }
    }
}

__global__ __launch_bounds__(256, 2)
void gemm_f16s_f32(const _Float16* __restrict__ Ah, const _Float16* __restrict__ Al,
                   int map_in, int m_off_in,
                   const _Float16* __restrict__ Wh, const _Float16* __restrict__ Wl,
                   const float* __restrict__ bias, float* __restrict__ C, int ldc,
                   int map_out, int m_off_out)
{
    gemm_core<0>(Ah, Al, Wh, Wl, bias, C, nullptr, nullptr, ldc,
                 map_in, m_off_in, map_out, m_off_out,
                 blockIdx.x * 128, blockIdx.y * 128);
}

// ---------------------------------------------------------------------------
// NEW split-f16 MFMA GEMM core, tile 256x128, BK=32, K=1024, 512 threads,
// 8 waves (4M x 2N, 64x64 per wave). Triple-buffered LDS (3 x 48 KB),
// single s_barrier per K-step, counted vmcnt(6) (prefetch depth 2).
// LDS XOR swizzle: 16B slot s of row r stored at s ^ ((r>>1)&3); staging
// inverse-swizzles the per-lane GLOBAL source so global_load_lds keeps its
// linear wave-uniform destination (rule: both-sides-or-neither).
// EPI 1: split-f16 [row][1024] (scatter map). EPI 3: C^T split-f16 [n][8192].
// ---------------------------------------------------------------------------
template<int EPI>
__device__ __forceinline__ void gemm256_core(
    uint32_t* __restrict__ smem_u,
    const _Float16* __restrict__ Ah, const _Float16* __restrict__ Al,
    const _Float16* __restrict__ Wh, const _Float16* __restrict__ Wl,
    const float* __restrict__ bias,
    _Float16* __restrict__ Ch, _Float16* __restrict__ Cl,
    int map_in, int m_off_in, int map_out, int m_off_out,
    int n0, int m0)
{
    _Float16* S = (_Float16*)smem_u;
    const int tid  = threadIdx.x;
    const int lane = tid & 63;
    const int wv = tid >> 6;          // 0..7
    const int wm = wv >> 1;           // 0..3 (M quadrant)
    const int fm = wm << 6;
    const int fn = (wv & 1) << 6;     // 0/64 (N half)
    const int lm = lane & 15, lq = lane >> 4;
    const int ko = ((lq ^ ((lm >> 1) & 3)) << 3);   // swizzled k-slot (f16)

    f32x4 acc[4][4] = {};

    // staging: 512 thr x 16B; rows srow and srow+128; source k-slot
    // inverse-swizzled so linear LDS dest holds swizzled layout.
    const int srow = tid >> 2;
    const int scol = (((tid & 3) ^ ((tid >> 3) & 3)) << 3);
    const int gm0 = m_off_in + m0 + srow;
    const int gm1 = gm0 + 128;
    const int r0 = map_in ? tmap_dev(gm0) : gm0;
    const int r1 = map_in ? tmap_dev(gm1) : gm1;
    const _Float16* gAh0 = Ah + (size_t)r0 * 1024 + scol;
    const _Float16* gAh1 = Ah + (size_t)r1 * 1024 + scol;
    const _Float16* gAl0 = Al + (size_t)r0 * 1024 + scol;
    const _Float16* gAl1 = Al + (size_t)r1 * 1024 + scol;
    const _Float16* gBh  = Wh + (size_t)(n0 + srow) * 1024 + scol;
    const _Float16* gBl  = Wl + (size_t)(n0 + srow) * 1024 + scol;
    const int lo = tid << 3;

    // buffer b (48 KB = 24576 f16): Ah[0,8192) Al[8192,16384) Bh[16384,20480) Bl[20480,24576)
    auto stage = [&](int t, int b) {
        const int k0 = t << 5;
        _Float16* d = S + b * 24576;
        load16(gAh0 + k0, d + lo);
        load16(gAh1 + k0, d + 4096  + lo);
        load16(gAl0 + k0, d + 8192  + lo);
        load16(gAl1 + k0, d + 12288 + lo);
        load16(gBh  + k0, d + 16384 + lo);
        load16(gBl  + k0, d + 20480 + lo);
    };

    auto kstep = [&](int t, int cb, int sb, bool last) {
        // lgkmcnt(0): all my ds_reads of tile t-1 retired -> after the
        // barrier it is safe for any wave to overwrite buf (t-1)%3 (== sb).
        // vmcnt(6): the 6 oldest loads (tile t) have landed; tile t+1's 6
        // stay in flight across the barrier (counted, never drain to 0).
        if (last) asm volatile("s_waitcnt vmcnt(0) lgkmcnt(0)" ::: "memory");
        else      asm volatile("s_waitcnt vmcnt(6) lgkmcnt(0)" ::: "memory");
        __builtin_amdgcn_s_barrier();
        if (sb >= 0) stage(t + 2, sb);

        const _Float16* c = S + cb * 24576;
        f16x8 ah[4], al[4], bh[4], bl[4];
        #pragma unroll
        for (int i = 0; i < 4; i++) {
            int ra = (fm + i * 16 + lm) * 32 + ko;
            ah[i] = *(const f16x8*)(c + ra);
            al[i] = *(const f16x8*)(c + 8192 + ra);
            int rb = (fn + i * 16 + lm) * 32 + ko;
            bh[i] = *(const f16x8*)(c + 16384 + rb);
            bl[i] = *(const f16x8*)(c + 20480 + rb);
        }
        __builtin_amdgcn_s_setprio(1);
        #pragma unroll
        for (int i = 0; i < 4; i++)
            #pragma unroll
            for (int j = 0; j < 4; j++) {
                acc[i][j] = __builtin_amdgcn_mfma_f32_16x16x32_f16(ah[i], bh[j], acc[i][j], 0, 0, 0);
                acc[i][j] = __builtin_amdgcn_mfma_f32_16x16x32_f16(ah[i], bl[j], acc[i][j], 0, 0, 0);
                acc[i][j] = __builtin_amdgcn_mfma_f32_16x16x32_f16(al[i], bh[j], acc[i][j], 0, 0, 0);
            }
        __builtin_amdgcn_s_setprio(0);
    };

    stage(0, 0);
    stage(1, 1);
    #pragma unroll 1
    for (int tt = 0; tt < 30; tt += 3) {
        kstep(tt + 0, 0, 2, false);
        kstep(tt + 1, 1, 0, false);
        kstep(tt + 2, 2, 1, false);
    }
    kstep(30, 0, -1, false);
    kstep(31, 1, -1, true);

    if (EPI == 1) {
        #pragma unroll
        for (int j = 0; j < 4; j++) {
            int n = n0 + fn + j * 16 + lm;
            float bb = bias[n];
            #pragma unroll
            for (int i = 0; i < 4; i++) {
                #pragma unroll
                for (int r = 0; r < 4; r++) {
                    int gm = m_off_out + m0 + fm + i * 16 + lq * 4 + r;
                    int row = map_out ? tmap_dev(gm) : gm;
                    float v = acc[i][j][r] + bb;
                    _Float16 h, l;
                    split_f16(v, h, l);
                    Ch[(size_t)row * 1024 + n] = h;
                    Cl[(size_t)row * 1024 + n] = l;
                }
            }
        }
    } else {
        // EPI 3: write C^T split-f16 [n0+nn][8192], LDS transpose in 4 rounds
        // over M quadrants. [64][129] u32 region sits inside buf0; tile 31
        // used buf1, and __syncthreads drains everything anyway.
        #pragma unroll 1
        for (int q = 0; q < 4; q++) {
            __syncthreads();
            if (wm == q) {
                #pragma unroll
                for (int j = 0; j < 4; j++) {
                    int ncol = fn + j * 16 + lm;
                    float bb = bias[n0 + ncol];
                    #pragma unroll
                    for (int i = 0; i < 4; i++) {
                        #pragma unroll
                        for (int r = 0; r < 4; r++) {
                            float v = acc[i][j][r] + bb;
                            _Float16 h, l;
                            split_f16(v, h, l);
                            uint32_t ph = (uint32_t)__builtin_bit_cast(unsigned short, h);
                            uint32_t pl = (uint32_t)__builtin_bit_cast(unsigned short, l);
                            smem_u[(i * 16 + lq * 4 + r) * 129 + ncol] = ph | (pl << 16);
                        }
                    }
                }
            }
            __syncthreads();
            #pragma unroll
            for (int g = 0; g < 4; g++) {
                int u = tid + g * 512;
                int nn = u >> 4;            // 0..127
                int mg = (u & 15) << 2;     // 0..60
                uint32_t p0 = smem_u[(mg + 0) * 129 + nn];
                uint32_t p1 = smem_u[(mg + 1) * 129 + nn];
                uint32_t p2 = smem_u[(mg + 2) * 129 + nn];
                uint32_t p3 = smem_u[(mg + 3) * 129 + nn];
                f16x4 hh, ll;
                hh[0] = __builtin_bit_cast(_Float16, (unsigned short)(p0 & 0xffff));
                hh[1] = __builtin_bit_cast(_Float16, (unsigned short)(p1 & 0xffff));
                hh[2] = __builtin_bit_cast(_Float16, (unsigned short)(p2 & 0xffff));
                hh[3] = __builtin_bit_cast(_Float16, (unsigned short)(p3 & 0xffff));
                ll[0] = __builtin_bit_cast(_Float16, (unsigned short)(p0 >> 16));
                ll[1] = __builtin_bit_cast(_Float16, (unsigned short)(p1 >> 16));
                ll[2] = __builtin_bit_cast(_Float16, (unsigned short)(p2 >> 16));
                ll[3] = __builtin_bit_cast(_Float16, (unsigned short)(p3 >> 16));
                size_t off = (size_t)(n0 + nn) * 8192 + (m0 + q * 64 + mg);
                *(f16x4*)(Ch + off) = hh;
                *(f16x4*)(Cl + off) = ll;
            }
        }
    }
}

// QKV projection: z=0 -> Qh/Ql, z=1 -> Kh/Kl, z=2 -> VT (transposed).
// 1-D grid 768 = 8 XCD chunks x 96; wg = z*256 + my*8 + nx (x fastest so an
// XCD's chunk reuses each A panel across the 8 n-tiles from its own L2).
__global__ __launch_bounds__(512, 2)
void gemm_qkv256(const _Float16* __restrict__ Ah, const _Float16* __restrict__ Al,
                 int map_in, int m_off_in,
                 const _Float16* __restrict__ WTh, const _Float16* __restrict__ WTl,
                 const float* __restrict__ bq, const float* __restrict__ bk,
                 const float* __restrict__ bv,
                 _Float16* __restrict__ Qh, _Float16* __restrict__ Ql,
                 _Float16* __restrict__ Kh, _Float16* __restrict__ Kl,
                 _Float16* __restrict__ VTh, _Float16* __restrict__ VTl)
{
    __shared__ uint32_t smem_u[36864];   // 144 KB: 3 x 48 KB K-loop buffers
    const int bid = blockIdx.x;
    const int wg = (bid & 7) * 96 + (bid >> 3);   // bijective: 768 % 8 == 0
    const int z = wg >> 8;
    const int rem = wg & 255;
    const int m0 = (rem >> 3) << 8;
    const int n0 = (rem & 7) << 7;
    const _Float16* wh = WTh + (size_t)z * 1048576;
    const _Float16* wl = WTl + (size_t)z * 1048576;
    if (z < 2) {
        const float* bb = (z == 0) ? bq : bk;
        _Float16* oh = (z == 0) ? Qh : Kh;
        _Float16* ol = (z == 0) ? Ql : Kl;
        gemm256_core<1>(smem_u, Ah, Al, wh, wl, bb, oh, ol,
                        map_in, m_off_in, 0, 0, n0, m0);
    } else {
        gemm256_core<3>(smem_u, Ah, Al, wh, wl, bv, VTh, VTl,
                        map_in, m_off_in, 0, 0, n0, m0);
    }
}

// Output projection: grid 256 (= 8 XCD chunks x 32), one block per CU.
__global__ __launch_bounds__(512, 2)
void gemm_h256(const _Float16* __restrict__ Ah, const _Float16* __restrict__ Al,
               int map_in, int m_off_in,
               const _Float16* __restrict__ Wh, const _Float16* __restrict__ Wl,
               const float* __restrict__ bias,
               _Float16* __restrict__ Ch, _Float16* __restrict__ Cl,
               int map_out, int m_off_out)
{
    __shared__ uint32_t smem_u[36864];
    const int bid = blockIdx.x;
    const int wg = (bid & 7) * 32 + (bid >> 3);   // bijective: 256 % 8 == 0
    const int m0 = (wg >> 3) << 8;
    const int n0 = (wg & 7) << 7;
    gemm256_core<1>(smem_u, Ah, Al, Wh, Wl, bias, Ch, Cl,
                    map_in, m_off_in, map_out, m_off_out, n0, m0);
}

// ---------------------------------------------------------------------------
// Spatial attention via MFMA, S=256. One workgroup per (frame, head).
// ---------------------------------------------------------------------------
__global__ __launch_bounds__(256, 2)
void attn_s_m(const _Float16* __restrict__ Qh, const _Float16* __restrict__ Ql,
              const _Float16* __restrict__ Kh, const _Float16* __restrict__ Kl,
              const _Float16* __restrict__ VTh, const _Float16* __restrict__ VTl,
              const float* __restrict__ RB,
              _Float16* __restrict__ Ch, _Float16* __restrict__ Cl)
{
    __shared__ _Float16 sKh[2048], sKl[2048];      // [32 j][64 d]
    __shared__ _Float16 sVh[2560], sVl[2560];      // [64 d][40] (32 j + pad)
    __shared__ _Float16 sPh[4][2560], sPl[4][2560];// per-wave [64 s][40]
    __shared__ float Bt[512];

    const int tid = threadIdx.x;
    const int lane = tid & 63;
    const int w = tid >> 6;
    const int lm = lane & 15, lq = lane >> 4;
    const int frame = blockIdx.x;
    const int h = blockIdx.y;
    const int rowbase = frame * 256;

    #pragma unroll
    for (int l = 0; l < 2; l++) {
        int idx = tid + l * 256;
        if (idx < 511) Bt[idx] = RB[(size_t)(256 + idx) * 16 + h];
    }

    // Q B-frags in registers
    f16x8 qbh[4][2], qbl[4][2];
    #pragma unroll
    for (int st = 0; st < 4; st++)
        #pragma unroll
        for (int kk = 0; kk < 2; kk++) {
            size_t qo = (size_t)(rowbase + w * 64 + st * 16 + lm) * 1024
                        + h * 64 + kk * 32 + lq * 8;
            qbh[st][kk] = *(const f16x8*)(Qh + qo);
            qbl[st][kk] = *(const f16x8*)(Ql + qo);
        }

    f32x4 cacc[4][4] = {};
    float lsum[4] = {0.f, 0.f, 0.f, 0.f};
    _Float16* Ph = sPh[w];
    _Float16* Pl = sPl[w];

    const int skrow = tid >> 3, skd = (tid & 7) << 3;
    const int svrow = tid >> 2, svj = (tid & 3) << 3;

    for (int jc = 0; jc < 8; jc++) {
        __syncthreads();
        {
            size_t ko = (size_t)(rowbase + jc * 32 + skrow) * 1024 + h * 64 + skd;
            *(f16x8*)(sKh + skrow * 64 + skd) = *(const f16x8*)(Kh + ko);
            *(f16x8*)(sKl + skrow * 64 + skd) = *(const f16x8*)(Kl + ko);
            size_t vo = (size_t)(h * 64 + svrow) * 8192 + rowbase + jc * 32 + svj;
            *(f16x8*)(sVh + svrow * 40 + svj) = *(const f16x8*)(VTh + vo);
            *(f16x8*)(sVl + svrow * 40 + svj) = *(const f16x8*)(VTl + vo);
        }
        __syncthreads();

        // S^T = K @ Q^T
        f32x4 sacc[2][4] = {};
        #pragma unroll
        for (int jt = 0; jt < 2; jt++) {
            f16x8 kah[2], kal[2];
            #pragma unroll
            for (int kk = 0; kk < 2; kk++) {
                int ra = (jt * 16 + lm) * 64 + kk * 32 + lq * 8;
                kah[kk] = *(const f16x8*)(sKh + ra);
                kal[kk] = *(const f16x8*)(sKl + ra);
            }
            #pragma unroll
            for (int st = 0; st < 4; st++)
                #pragma unroll
                for (int kk = 0; kk < 2; kk++) {
                    sacc[jt][st] = __builtin_amdgcn_mfma_f32_16x16x32_f16(kah[kk], qbh[st][kk], sacc[jt][st], 0, 0, 0);
                    sacc[jt][st] = __builtin_amdgcn_mfma_f32_16x16x32_f16(kah[kk], qbl[st][kk], sacc[jt][st], 0, 0, 0);
                    sacc[jt][st] = __builtin_amdgcn_mfma_f32_16x16x32_f16(kal[kk], qbh[st][kk], sacc[jt][st], 0, 0, 0);
                }
        }

        // bias + exp + pack P into per-wave LDS ([s][40], j-consecutive)
        #pragma unroll
        for (int jt = 0; jt < 2; jt++)
            #pragma unroll
            for (int st = 0; st < 4; st++) {
                f16x4 p4h, p4l;
                #pragma unroll
                for (int r = 0; r < 4; r++) {
                    int j = jc * 32 + jt * 16 + lq * 4 + r;
                    int s = w * 64 + st * 16 + lm;
                    float p = __expf(sacc[jt][st][r] * 0.125f + Bt[j - s + 255]);
                    lsum[st] += p;
                    _Float16 hp, lp;
                    split_f16(p, hp, lp);
                    p4h[r] = hp; p4l[r] = lp;
                }
                int pa = (st * 16 + lm) * 40 + jt * 16 + lq * 4;
                *(f16x4*)(Ph + pa) = p4h;
                *(f16x4*)(Pl + pa) = p4l;
            }

        // ctx^T += V^T @ P^T
        #pragma unroll
        for (int st = 0; st < 4; st++) {
            int pb = (st * 16 + lm) * 40 + lq * 8;
            f16x8 pbh = *(const f16x8*)(Ph + pb);
            f16x8 pbl = *(const f16x8*)(Pl + pb);
            #pragma unroll
            for (int dt = 0; dt < 4; dt++) {
                int va = (dt * 16 + lm) * 40 + lq * 8;
                f16x8 vah = *(const f16x8*)(sVh + va);
                f16x8 val = *(const f16x8*)(sVl + va);
                cacc[dt][st] = __builtin_amdgcn_mfma_f32_16x16x32_f16(vah, pbh, cacc[dt][st], 0, 0, 0);
                cacc[dt][st] = __builtin_amdgcn_mfma_f32_16x16x32_f16(vah, pbl, cacc[dt][st], 0, 0, 0);
                cacc[dt][st] = __builtin_amdgcn_mfma_f32_16x16x32_f16(val, pbh, cacc[dt][st], 0, 0, 0);
            }
        }
    }

    float inv[4];
    #pragma unroll
    for (int st = 0; st < 4; st++) {
        float t = lsum[st];
        t += __shfl_xor(t, 16);
        t += __shfl_xor(t, 32);
        inv[st] = 1.0f / t;
    }

    #pragma unroll
    for (int st = 0; st < 4; st++)
        #pragma unroll
        for (int dt = 0; dt < 4; dt++) {
            f16x4 oh, ol;
            #pragma unroll
            for (int r = 0; r < 4; r++) {
                _Float16 hp, lp;
                split_f16(cacc[dt][st][r] * inv[st], hp, lp);
                oh[r] = hp; ol[r] = lp;
            }
            size_t oo = (size_t)(rowbase + w * 64 + st * 16 + lm) * 1024
                        + h * 64 + dt * 16 + lq * 4;
            *(f16x4*)(Ch + oo) = oh;
            *(f16x4*)(Cl + oo) = ol;
        }
}

// ---------------------------------------------------------------------------
// Temporal attention via MFMA, S=32.
// ---------------------------------------------------------------------------
__global__ __launch_bounds__(256, 2)
void attn_t_m(const _Float16* __restrict__ Qh, const _Float16* __restrict__ Ql,
              const _Float16* __restrict__ Kh, const _Float16* __restrict__ Kl,
              const _Float16* __restrict__ VTh, const _Float16* __restrict__ VTl,
              const float* __restrict__ RB,
              _Float16* __restrict__ Ch, _Float16* __restrict__ Cl)
{
    __shared__ _Float16 sPh[4][1280], sPl[4][1280];
    __shared__ float Bt[64];

    const int tid = threadIdx.x;
    const int lane = tid & 63;
    const int w = tid >> 6;
    const int lm = lane & 15, lq = lane >> 4;
    const int h = blockIdx.y;
    const int bx = blockIdx.x * 4 + w;
    const int rowbase = bx * 32;

    if (tid < 63) Bt[tid] = RB[(size_t)(480 + tid) * 16 + h];
    __syncthreads();

    f16x8 qbh[2][2], qbl[2][2];
    #pragma unroll
    for (int st = 0; st < 2; st++)
        #pragma unroll
        for (int kk = 0; kk < 2; kk++) {
            size_t qo = (size_t)(rowbase + st * 16 + lm) * 1024 + h * 64 + kk * 32 + lq * 8;
            qbh[st][kk] = *(const f16x8*)(Qh + qo);
            qbl[st][kk] = *(const f16x8*)(Ql + qo);
        }

    f32x4 sacc[2][2] = {};
    #pragma unroll
    for (int jt = 0; jt < 2; jt++) {
        f16x8 kah[2], kal[2];
        #pragma unroll
        for (int kk = 0; kk < 2; kk++) {
            size_t ko = (size_t)(rowbase + jt * 16 + lm) * 1024 + h * 64 + kk * 32 + lq * 8;
            kah[kk] = *(const f16x8*)(Kh + ko);
            kal[kk] = *(const f16x8*)(Kl + ko);
        }
        #pragma unroll
        for (int st = 0; st < 2; st++)
            #pragma unroll
            for (int kk = 0; kk < 2; kk++) {
                sacc[jt][st] = __builtin_amdgcn_mfma_f32_16x16x32_f16(kah[kk], qbh[st][kk], sacc[jt][st], 0, 0, 0);
                sacc[jt][st] = __builtin_amdgcn_mfma_f32_16x16x32_f16(kah[kk], qbl[st][kk], sacc[jt][st], 0, 0, 0);
                sacc[jt][st] = __builtin_amdgcn_mfma_f32_16x16x32_f16(kal[kk], qbh[st][kk], sacc[jt][st], 0, 0, 0);
            }
    }

    float lsum[2] = {0.f, 0.f};
    _Float16* Ph = sPh[w];
    _Float16* Pl = sPl[w];
    #pragma unroll
    for (int jt = 0; jt < 2; jt++)
        #pragma unroll
        for (int st = 0; st < 2; st++) {
            f16x4 p4h, p4l;
            #pragma unroll
            for (int r = 0; r < 4; r++) {
                int j = jt * 16 + lq * 4 + r;
                int s = st * 16 + lm;
                float p = __expf(sacc[jt][st][r] * 0.125f + Bt[j - s + 31]);
                lsum[st] += p;
                _Float16 hp, lp;
                split_f16(p, hp, lp);
                p4h[r] = hp; p4l[r] = lp;
            }
            int pa = (st * 16 + lm) * 40 + jt * 16 + lq * 4;
            *(f16x4*)(Ph + pa) = p4h;
            *(f16x4*)(Pl + pa) = p4l;
        }

    f16x8 vah[4], val[4];
    #pragma unroll
    for (int dt = 0; dt < 4; dt++) {
        size_t vo = (size_t)(h * 64 + dt * 16 + lm) * 8192 + rowbase + lq * 8;
        vah[dt] = *(const f16x8*)(VTh + vo);
        val[dt] = *(const f16x8*)(VTl + vo);
    }
    f32x4 cacc[4][2] = {};
    #pragma unroll
    for (int st = 0; st < 2; st++) {
        int pb = (st * 16 + lm) * 40 + lq * 8;
        f16x8 pbh = *(const f16x8*)(Ph + pb);
        f16x8 pbl = *(const f16x8*)(Pl + pb);
        #pragma unroll
        for (int dt = 0; dt < 4; dt++) {
            cacc[dt][st] = __builtin_amdgcn_mfma_f32_16x16x32_f16(vah[dt], pbh, cacc[dt][st], 0, 0, 0);
            cacc[dt][st] = __builtin_amdgcn_mfma_f32_16x16x32_f16(vah[dt], pbl, cacc[dt][st], 0, 0, 0);
            cacc[dt][st] = __builtin_amdgcn_mfma_f32_16x16x32_f16(val[dt], pbh, cacc[dt][st], 0, 0, 0);
        }
    }

    float inv[2];
    #pragma unroll
    for (int st = 0; st < 2; st++) {
        float t = lsum[st];
        t += __shfl_xor(t, 16);
        t += __shfl_xor(t, 32);
        inv[st] = 1.0f / t;
    }

    #pragma unroll
    for (int st = 0; st < 2; st++)
        #pragma unroll
        for (int dt = 0; dt < 4; dt++) {
            f16x4 oh, ol;
            #pragma unroll
            for (int r = 0; r < 4; r++) {
                _Float16 hp, lp;
                split_f16(cacc[dt][st][r] * inv[st], hp, lp);
                oh[r] = hp; ol[r] = lp;
            }
            size_t oo = (size_t)(rowbase + st * 16 + lm) * 1024 + h * 64 + dt * 16 + lq * 4;
            *(f16x4*)(Ch + oo) = oh;
            *(f16x4*)(Cl + oo) = ol;
        }
}

// ---------------------------------------------------------------------------
// Token selection (unchanged)
// ---------------------------------------------------------------------------
__global__ __launch_bounds__(256)
void colsum_part_kernel(const float* __restrict__ SC, float* __restrict__ P)
{
    int bid = blockIdx.x;
    int b = bid >> 7, chunk = bid & 127;
    int base = b * 8192 + chunk * 64;
    int k = threadIdx.x;
    float sum = 0.0f;
    for (int r = 0; r < 64; r++)
        sum += __expf(SC[(size_t)(base + r) * 256 + k]);
    P[(size_t)bid * 256 + k] = sum;
}

__global__ __launch_bounds__(256)
void colsum_reduce_kernel(const float* __restrict__ P, float* __restrict__ CS)
{
    int b = blockIdx.x;
    int k = threadIdx.x;
    float s = 0.0f;
    for (int c = 0; c < 128; c++)
        s += P[(size_t)(b * 128 + c) * 256 + k];
    CS[b * 256 + k] = s;
}

__global__ __launch_bounds__(256)
void trans_wts(const float* __restrict__ SC, const float* __restrict__ CS,
               _Float16* __restrict__ Th, _Float16* __restrict__ Tl)
{
    __shared__ float L[64][65];
    const int mt = blockIdx.x * 64;
    const int kt = blockIdx.y * 64;
    const int b  = mt >> 13;
    const int ml = mt & 8191;
    const int tid = threadIdx.x;
    #pragma unroll
    for (int l = 0; l < 4; l++) {
        int idx = tid + 256 * l;
        int r = idx >> 4, c4 = (idx & 15) << 2;
        float4 v = *(const float4*)(SC + (size_t)(mt + r) * 256 + kt + c4);
        L[r][c4 + 0] = __expf(v.x); L[r][c4 + 1] = __expf(v.y);
        L[r][c4 + 2] = __expf(v.z); L[r][c4 + 3] = __expf(v.w);
    }
    __syncthreads();
    #pragma unroll
    for (int l = 0; l < 4; l++) {
        int idx = tid + 256 * l;
        int rk = idx >> 4, c4 = (idx & 15) << 2;
        float inv = 1.0f / CS[b * 256 + kt + rk];
        f16x4 hh, ll;
        #pragma unroll
        for (int u = 0; u < 4; u++) {
            _Float16 h, l2;
            split_f16(L[c4 + u][rk] * inv, h, l2);
            hh[u] = h; ll[u] = l2;
        }
        size_t o = ((size_t)b * 256 + kt + rk) * 8192 + ml + c4;
        *(f16x4*)(Th + o) = hh;
        *(f16x4*)(Tl + o) = ll;
    }
}

__global__ __launch_bounds__(256)
void trans_f16(const _Float16* __restrict__ Sh, const _Float16* __restrict__ Sl,
               _Float16* __restrict__ Th, _Float16* __restrict__ Tl)
{
    __shared__ _Float16 L[64][72];
    const int mt = blockIdx.x * 64, et = blockIdx.y * 64;
    const _Float16* S = blockIdx.z ? Sl : Sh;
    _Float16* T = blockIdx.z ? Tl : Th;
    const int tid = threadIdx.x;
    #pragma unroll
    for (int l = 0; l < 2; l++) {
        int v = tid * 2 + l;
        int r = v >> 3, c8 = (v & 7) << 3;
        *(f16x8*)&L[r][c8] = *(const f16x8*)(S + (size_t)(mt + r) * 1024 + et + c8);
    }
    __syncthreads();
    #pragma unroll
    for (int l = 0; l < 2; l++) {
        int v = tid * 2 + l;
        int r = v >> 3, c8 = (v & 7) << 3;
        f16x8 o;
        #pragma unroll
        for (int u = 0; u < 8; u++) o[u] = L[c8 + u][r];
        *(f16x8*)(T + (size_t)(et + r) * 16384 + mt + c8) = o;
    }
}

__global__ __launch_bounds__(256, 2)
void gemm_selm(const _Float16* __restrict__ Wth, const _Float16* __restrict__ Wtl,
               const _Float16* __restrict__ Hth, const _Float16* __restrict__ Htl,
               float* __restrict__ P)
{
    __shared__ _Float16 sAh[4096], sAl[4096], sBh[4096], sBl[4096];
    const int tid = threadIdx.x;
    const int lane = tid & 63;
    const int wv = tid >> 6;
    const int fm = (wv >> 1) << 6;
    const int fn = (wv & 1) << 6;
    const int lm = lane & 15, lq = lane >> 4;
    const int n0 = blockIdx.x * 128;
    const int m0 = blockIdx.y * 128;
    const int z  = blockIdx.z;
    const int b = z >> 3, sp = z & 7;

    f32x4 acc[4][4] = {};

    const int srow = tid >> 2;
    const int skc  = (tid & 3) << 3;
    const _Float16* gAh0 = Wth + ((size_t)b * 256 + m0 + srow) * 8192 + sp * 1024 + skc;
    const _Float16* gAl0 = Wtl + ((size_t)b * 256 + m0 + srow) * 8192 + sp * 1024 + skc;
    const _Float16* gB0 = Hth + (size_t)(n0 + srow) * 16384 + b * 8192 + sp * 1024 + skc;
    const _Float16* gB1 = Htl + (size_t)(n0 + srow) * 16384 + b * 8192 + sp * 1024 + skc;
    const int lo = tid << 3;

    for (int k0 = 0; k0 < 1024; k0 += 32) {
        load16(gAh0 + k0,          sAh + lo);
        load16(gAh0 + k0 + 524288, sAh + lo + 2048);
        load16(gAl0 + k0,          sAl + lo);
        load16(gAl0 + k0 + 524288, sAl + lo + 2048);
        load16(gB0 + k0,           sBh + lo);
        load16(gB0 + k0 + 1048576, sBh + lo + 2048);
        load16(gB1 + k0,           sBl + lo);
        load16(gB1 + k0 + 1048576, sBl + lo + 2048);
        __syncthreads();

        f16x8 ah[4], al[4], bh[4], bl[4];
        #pragma unroll
        for (int i = 0; i < 4; i++) {
            int ra = (fm + i * 16 + lm) * 32 + lq * 8;
            ah[i] = *(const f16x8*)(sAh + ra);
            al[i] = *(const f16x8*)(sAl + ra);
            int rb_ = (fn + i * 16 + lm) * 32 + lq * 8;
            bh[i] = *(const f16x8*)(sBh + rb_);
            bl[i] = *(const f16x8*)(sBl + rb_);
        }
        #pragma unroll
        for (int i = 0; i < 4; i++)
            #pragma unroll
            for (int j = 0; j < 4; j++) {
                acc[i][j] = __builtin_amdgcn_mfma_f32_16x16x32_f16(ah[i], bh[j], acc[i][j], 0, 0, 0);
                acc[i][j] = __builtin_amdgcn_mfma_f32_16x16x32_f16(ah[i], bl[j], acc[i][j], 0, 0, 0);
                acc[i][j] = __builtin_amdgcn_mfma_f32_16x16x32_f16(al[i], bh[j], acc[i][j], 0, 0, 0);
            }
        __syncthreads();
    }

    float* Pz = P + (size_t)z * 262144;
    #pragma unroll
    for (int j = 0; j < 4; j++) {
        int n = n0 + fn + j * 16 + lm;
        #pragma unroll
        for (int i = 0; i < 4; i++)
            #pragma unroll
            for (int r = 0; r < 4; r++) {
                int k = m0 + fm + i * 16 + lq * 4 + r;
                Pz[(size_t)k * 1024 + n] = acc[i][j][r];
            }
    }
}

__global__ __launch_bounds__(256)
void sel_reduce(const float* __restrict__ P, float* __restrict__ SEL)
{
    int idx4 = blockIdx.x * 256 + threadIdx.x;
    int e = idx4 << 2;
    int b = e >> 18;
    int rest = e & 262143;
    const float* p = P + (size_t)(b * 8) * 262144 + rest;
    float4 acc = {0.f, 0.f, 0.f, 0.f};
    #pragma unroll
    for (int s = 0; s < 8; s++) {
        float4 v = *(const float4*)(p + (size_t)s * 262144);
        acc.x += v.x; acc.y += v.y; acc.z += v.z; acc.w += v.w;
    }
    *(float4*)(SEL + e) = acc;
}

__global__ __launch_bounds__(256)
void pool_kernel(const float* __restrict__ SEL, float* __restrict__ out)
{
    int i4 = blockIdx.x * 256 + threadIdx.x;
    int e  = i4 << 2;
    int row = e >> 10;
    int b = row / 448;
    int r = row - b * 448;
    int c = e & 1023;
    const float* sb = SEL + (size_t)b * (256 * 1024);
    float4 o;
    if (r < 256) {
        o = *(const float4*)(sb + (size_t)r * 1024 + c);
    } else if (r < 384) {
        int r2 = (r - 256) * 2;
        float4 x0 = *(const float4*)(sb + (size_t)r2 * 1024 + c);
        float4 x1 = *(const float4*)(sb + (size_t)(r2 + 1) * 1024 + c);
        o.x = 0.5f * (x0.x + x1.x); o.y = 0.5f * (x0.y + x1.y);
        o.z = 0.5f * (x0.z + x1.z); o.w = 0.5f * (x0.w + x1.w);
    } else {
        int r4 = (r - 384) * 4;
        float4 x0 = *(const float4*)(sb + (size_t)(r4 + 0) * 1024 + c);
        float4 x1 = *(const float4*)(sb + (size_t)(r4 + 1) * 1024 + c);
        float4 x2 = *(const float4*)(sb + (size_t)(r4 + 2) * 1024 + c);
        float4 x3 = *(const float4*)(sb + (size_t)(r4 + 3) * 1024 + c);
        o.x = 0.25f * (x0.x + x1.x + x2.x + x3.x);
        o.y = 0.25f * (x0.y + x1.y + x2.y + x3.y);
        o.z = 0.25f * (x0.z + x1.z + x2.z + x3.z);
        o.w = 0.25f * (x0.w + x1.w + x2.w + x3.w);
    }
    *(float4*)(out + e) = o;
}

// ---------------------------------------------------------------------------
extern "C" void kernel_launch(void* const* d_in, const int* in_sizes, int n_in,
                              void* d_out, int out_size, void* d_ws, size_t ws_size,
                              hipStream_t stream)
{
    const float* x    = (const float*)d_in[0];
    const float* wq   = (const float*)d_in[1];
    const float* bq   = (const float*)d_in[2];
    const float* wk   = (const float*)d_in[3];
    const float* bk   = (const float*)d_in[4];
    const float* wv   = (const float*)d_in[5];
    const float* bv   = (const float*)d_in[6];
    const float* wd   = (const float*)d_in[7];
    const float* bd   = (const float*)d_in[8];
    const float* rb   = (const float*)d_in[9];
    const float* selw = (const float*)d_in[10];
    const float* selb = (const float*)d_in[11];
    float* out = (float*)d_out;

    float* base = (float*)d_ws;
    _Float16* Hh  = (_Float16*)base;
    _Float16* Hl  = Hh + 16777216;
    _Float16* Qh  = (_Float16*)(base + 16777216);
    _Float16* Ql  = Qh + 8388608;
    _Float16* Kh  = Ql + 8388608;
    _Float16* Kl  = Kh + 8388608;
    _Float16* VTh = (_Float16*)(base + 33554432);
    _Float16* VTl = VTh + 8388608;
    _Float16* CXh = (_Float16*)(base + 41943040);
    _Float16* CXl = CXh + 8388608;
    _Float16* WTh = (_Float16*)(base + 50331648);
    _Float16* WTl = WTh + 4194304;
    _Float16* Ah  = (_Float16*)(base + 54525952);
    _Float16* Al  = Ah + 8388608;
    float* SC   = (float*)Qh;
    float* Pp   = (float*)Kh;
    float* SEL  = (float*)Kl;
    float* PART = SEL + 524288;
    float* CSUM = PART + 65536;
    _Float16* WTTh = CXh;
    _Float16* WTTl = CXl;
    _Float16* HTh  = Ah;
    _Float16* HTl  = VTh;

    const dim3 blk(256);
    const dim3 blk2(512);

    for (int a = 0; a < 4; a++) {
        const int mi = (a & 1);
        const size_t wo = (size_t)a * 1048576;
        const int bo = a * 1024;
        const float* rba = rb + (size_t)a * 1023 * 16;

        conv_wT<<<dim3(16, 16), blk, 0, stream>>>(wq + wo, WTh,           WTl,           1024);
        conv_wT<<<dim3(16, 16), blk, 0, stream>>>(wk + wo, WTh + 1048576, WTl + 1048576, 1024);
        conv_wT<<<dim3(16, 16), blk, 0, stream>>>(wv + wo, WTh + 2097152, WTl + 2097152, 1024);
        conv_wT<<<dim3(16, 16), blk, 0, stream>>>(wd + wo, WTh + 3145728, WTl + 3145728, 1024);

        for (int c = 0; c < 2; c++) {
            const int mo = c * 8192;
            const _Float16 *sH, *sL;
            int sm, so;
            if (a == 0) {
                conv_act<<<4096, blk, 0, stream>>>(x, Ah, Al, mo);
                sH = Ah; sL = Al; sm = 0; so = 0;
            } else {
                sH = Hh; sL = Hl; sm = mi; so = mo;
            }
            gemm_qkv256<<<dim3(768), blk2, 0, stream>>>(
                sH, sL, sm, so, WTh, WTl, bq + bo, bk + bo, bv + bo,
                Qh, Ql, Kh, Kl, VTh, VTl);
            if (mi == 0)
                attn_s_m<<<dim3(32, 16), blk, 0, stream>>>(Qh, Ql, Kh, Kl, VTh, VTl, rba, CXh, CXl);
            else
                attn_t_m<<<dim3(64, 16), blk, 0, stream>>>(Qh, Ql, Kh, Kl, VTh, VTl, rba, CXh, CXl);
            gemm_h256<<<dim3(256), blk2, 0, stream>>>(
                CXh, CXl, 0, 0, WTh + 3145728, WTl + 3145728, bd + bo, Hh, Hl, mi, mo);
        }
    }

    // token selection
    conv_wT<<<dim3(4, 16), blk, 0, stream>>>(selw, WTh, WTl, 256);
    gemm_f16s_f32<<<dim3(2, 128), blk, 0, stream>>>(
        Hh, Hl, 0, 0, WTh, WTl, selb, SC, 256, 0, 0);
    colsum_part_kernel<<<256, blk, 0, stream>>>(SC, PART);
    colsum_reduce_kernel<<<2, blk, 0, stream>>>(PART, CSUM);
    trans_wts<<<dim3(256, 4), blk, 0, stream>>>(SC, CSUM, WTTh, WTTl);
    trans_f16<<<dim3(256, 16, 2), blk, 0, stream>>>(Hh, Hl, HTh, HTl);
    gemm_selm<<<dim3(8, 2, 16), blk, 0, stream>>>(WTTh, WTTl, HTh, HTl, Pp);
    sel_reduce<<<512, blk, 0, stream>>>(Pp, SEL);
    pool_kernel<<<896, blk, 0, stream>>>(SEL, out);
}